// Round 3
// baseline (1391.208 us; speedup 1.0000x reference)
//
#include <hip/hip_runtime.h>
#include <hip/hip_bf16.h>

// SurfaceLoss: 16x256x256 grid through 3->128->128->128->1 tanh MLP, MSE vs images.
// R3: transcendental-free tanh (Eigen rational P13/Q6, packed v_pk_fma_f32,
//     bit-trick reciprocal + 2 packed Newton), phi row-swizzle to kill epilogue
//     LDS bank conflicts, 2 launches (prep zeroes, main's last block reduces).

#define BATCH 16
#define LDA 136                 // padded LDS row stride (bf16 elems); rows 16B-aligned for b128
#define STEP (256.0f / 255.0f)  // linspace(-128,128,256) step

typedef __bf16 v8bf __attribute__((ext_vector_type(8)));
typedef float  v4f  __attribute__((ext_vector_type(4)));
typedef float  v2f  __attribute__((ext_vector_type(2)));

__device__ __forceinline__ unsigned short f2bf(float f) {
    unsigned int u = __float_as_uint(f);
    unsigned int r = (u + 0x7fffu + ((u >> 16) & 1u)) >> 16;
    return (unsigned short)r;
}

#if __has_builtin(__builtin_amdgcn_cvt_pk_bf16_f32)
__device__ __forceinline__ unsigned int pack2bf(float a, float b) {
    auto p = __builtin_amdgcn_cvt_pk_bf16_f32(a, b);   // lo=a, hi=b
    union { decltype(p) v; unsigned int u; } c; c.v = p;
    return c.u;
}
#else
__device__ __forceinline__ unsigned int pack2bf(float a, float b) {
    return (unsigned)f2bf(a) | ((unsigned)f2bf(b) << 16);
}
#endif

__device__ __forceinline__ v2f V2(float c) { return (v2f){c, c}; }

#if __has_builtin(__builtin_elementwise_fma)
#define FMA2(a, b, c) __builtin_elementwise_fma((a), (b), (c))
#else
__device__ __forceinline__ v2f FMA2(v2f a, v2f b, v2f c) {
    v2f r; r.x = __builtin_fmaf(a.x, b.x, c.x); r.y = __builtin_fmaf(a.y, b.y, c.y); return r;
}
#endif

// Two tanh at once: Eigen/XLA fast-tanh rational, all full-rate packed fp32.
// Division replaced by bit-trick reciprocal seed (~5% rel err) + 2 Newton steps (~7e-6).
__device__ __forceinline__ v2f tanh2(v2f x) {
    x.x = __builtin_amdgcn_fmed3f(x.x, -7.90531111f, 7.90531111f);
    x.y = __builtin_amdgcn_fmed3f(x.y, -7.90531111f, 7.90531111f);
    v2f x2 = x * x;
    v2f p = FMA2(x2, V2(-2.76076847742355e-16f), V2(2.00018790482477e-13f));
    p = FMA2(x2, p, V2(-8.60467152213735e-11f));
    p = FMA2(x2, p, V2(5.12229709037114e-08f));
    p = FMA2(x2, p, V2(1.48572235717979e-05f));
    p = FMA2(x2, p, V2(6.37261928875436e-04f));
    p = FMA2(x2, p, V2(4.89352455891786e-03f));
    p = p * x;
    v2f q = FMA2(x2, V2(1.19825839466702e-06f), V2(1.18534705686654e-04f));
    q = FMA2(x2, q, V2(2.26843463243900e-03f));
    q = FMA2(x2, q, V2(4.89352518554385e-03f));
    union { v2f f; unsigned int u[2]; } cq, cr;
    cq.f = q;
    cr.u[0] = 0x7EF311C3u - cq.u[0];   // q > 0 always (Q has positive coeffs, even powers)
    cr.u[1] = 0x7EF311C3u - cq.u[1];
    v2f r = cr.f;
    r = r * FMA2(-q, r, V2(2.0f));
    r = r * FMA2(-q, r, V2(2.0f));
    return p * r;
}

// phi: within-16 row permutation so epilogue's 4 quads hit 4 disjoint bank octets
// (68*delta_phi = 8 mod 32). Applied consistently to every A-row index.
__device__ __forceinline__ int phi16(int m) {
    return ((m >> 2) << 1) | (m & 1) | ((m & 2) << 2);
}

// ---- prep: W2,W3 (128x128 fp32 [k][n]) -> bf16 [n][k]; zero partials+counter ----
__global__ __launch_bounds__(256) void prep_kernel(
    const float* __restrict__ W2, const float* __restrict__ W3,
    unsigned short* __restrict__ w2t, unsigned short* __restrict__ w3t,
    float* __restrict__ partials, unsigned int* __restrict__ counter)
{
    int o = blockIdx.x * 256 + threadIdx.x;
    if (o < 1024) partials[o] = 0.f;
    if (o == 0) *counter = 0u;
    const float* src = (o < 16384) ? W2 : W3;
    unsigned short* dst = (o < 16384) ? w2t : w3t;
    int e = o & 16383;
    int k = e >> 7, n = e & 127;
    dst[n * 128 + k] = f2bf(src[e]);
}

// ---- main: one block (512 thr, 8 waves) = 128 consecutive pixels of one image row ----
__global__ __launch_bounds__(512, 8) void main_kernel(
    const float* __restrict__ images,
    const float* __restrict__ W1, const float* __restrict__ b1,
    const float* __restrict__ b2, const float* __restrict__ b3,
    const float* __restrict__ W4, const float* __restrict__ b4,
    const int*   __restrict__ np,
    const unsigned short* __restrict__ w2t,
    const unsigned short* __restrict__ w3t,
    float* __restrict__ partials, unsigned int* __restrict__ counter,
    float* __restrict__ out)
{
    __shared__ unsigned short A[128 * LDA];
    __shared__ float red[8];
    __shared__ unsigned int isLast;

    const int tid  = threadIdx.x;
    const int lane = tid & 63;
    const int w    = tid >> 6;        // wave 0..7, owns 16 output cols
    const int l15  = lane & 15;
    const int quad = lane >> 4;
    const int l15p = phi16(l15);      // physical row-within-16 for fragment reads

    const int bid = blockIdx.x;
    const int b   = bid >> 9;          // 512 blocks per image
    const int rem = bid & 511;
    const int r   = rem >> 1;          // image row (x index)
    const int c0  = (rem & 1) << 7;    // y base

    const float tv = (float)(b + np[0] * BATCH);
    const float xv = -128.f + (float)r * STEP;

    // ---- layer 1 (fp32): each thread 2 cols x 16 points, packed ----
    {
        const int lo = tid & 63;       // = lane; col pair j0 = 2*lo
        const int j0 = lo * 2;
        const int w16 = w * 16;        // this wave's 16 point-rows
        unsigned int* A32 = (unsigned int*)A;
        v2f wx2 = *(const v2f*)(W1 + j0);
        v2f wy2 = *(const v2f*)(W1 + 128 + j0);
        v2f wt2 = *(const v2f*)(W1 + 256 + j0);
        v2f bb2 = *(const v2f*)(b1 + j0);
        v2f cj = FMA2(V2(xv), wx2, FMA2(V2(tv), wt2, bb2));
        #pragma unroll
        for (int pi = 0; pi < 16; ++pi) {
            const int pl = w16 + pi;                         // logical point row
            const float yv = fmaf((float)(c0 + pl), STEP, -128.f);
            v2f t = tanh2(FMA2(V2(yv), wy2, cj));
            A32[(w16 + phi16(pi)) * (LDA / 2) + lo] = pack2bf(t.x, t.y);  // conflict-free b32
        }
    }
    __syncthreads();

    const int colw = w * 16 + l15;     // this lane's output column

    // ---- W2 B-fragments from L2 ([n][k] layout) ----
    v8bf wf[4];
    #pragma unroll
    for (int ks = 0; ks < 4; ++ks)
        wf[ks] = *(const v8bf*)(w2t + colw * 128 + ks * 32 + quad * 8);

    // ---- layer 2 MFMA ----
    v4f acc[8];
    #pragma unroll
    for (int mt = 0; mt < 8; ++mt) acc[mt] = (v4f){0.f, 0.f, 0.f, 0.f};
    #pragma unroll
    for (int ks = 0; ks < 4; ++ks) {
        #pragma unroll
        for (int mt = 0; mt < 8; ++mt) {
            v8bf af = *(const v8bf*)&A[(mt * 16 + l15p) * LDA + ks * 32 + quad * 8];
            acc[mt] = __builtin_amdgcn_mfma_f32_16x16x32_bf16(af, wf[ks], acc[mt], 0, 0, 0);
        }
    }

    // prefetch W3 fragments
    v8bf w3f[4];
    #pragma unroll
    for (int ks = 0; ks < 4; ++ks)
        w3f[ks] = *(const v8bf*)(w3t + colw * 128 + ks * 32 + quad * 8);
    __syncthreads();   // all waves done reading A

    // ---- epilogue 2: tanh(acc + b2) -> A, phi rows (quads on disjoint bank octets) ----
    {
        float bi = b2[colw];
        #pragma unroll
        for (int mt = 0; mt < 8; ++mt) {
            v2f zlo; zlo.x = acc[mt][0]; zlo.y = acc[mt][1];
            v2f zhi; zhi.x = acc[mt][2]; zhi.y = acc[mt][3];
            v2f t01 = tanh2(zlo + V2(bi));
            v2f t23 = tanh2(zhi + V2(bi));
            unsigned u01 = pack2bf(t01.x, t01.y);
            unsigned u23 = pack2bf(t23.x, t23.y);
            int rowb = (mt * 16 + quad * 2) * LDA + colw;   // phi: rg{0,1,2,3}->{0,1,8,9}
            A[rowb]           = (unsigned short)u01;
            A[rowb + LDA]     = (unsigned short)(u01 >> 16);
            A[rowb + 8 * LDA] = (unsigned short)u23;
            A[rowb + 9 * LDA] = (unsigned short)(u23 >> 16);
        }
    }
    __syncthreads();

    // ---- layer 3 MFMA ----
    #pragma unroll
    for (int mt = 0; mt < 8; ++mt) acc[mt] = (v4f){0.f, 0.f, 0.f, 0.f};
    #pragma unroll
    for (int ks = 0; ks < 4; ++ks) {
        #pragma unroll
        for (int mt = 0; mt < 8; ++mt) {
            v8bf af = *(const v8bf*)&A[(mt * 16 + l15p) * LDA + ks * 32 + quad * 8];
            acc[mt] = __builtin_amdgcn_mfma_f32_16x16x32_bf16(af, w3f[ks], acc[mt], 0, 0, 0);
        }
    }
    __syncthreads();

    // ---- epilogue 3 ----
    {
        float bi = b3[colw];
        #pragma unroll
        for (int mt = 0; mt < 8; ++mt) {
            v2f zlo; zlo.x = acc[mt][0]; zlo.y = acc[mt][1];
            v2f zhi; zhi.x = acc[mt][2]; zhi.y = acc[mt][3];
            v2f t01 = tanh2(zlo + V2(bi));
            v2f t23 = tanh2(zhi + V2(bi));
            unsigned u01 = pack2bf(t01.x, t01.y);
            unsigned u23 = pack2bf(t23.x, t23.y);
            int rowb = (mt * 16 + quad * 2) * LDA + colw;
            A[rowb]           = (unsigned short)u01;
            A[rowb + LDA]     = (unsigned short)(u01 >> 16);
            A[rowb + 8 * LDA] = (unsigned short)u23;
            A[rowb + 9 * LDA] = (unsigned short)(u23 >> 16);
        }
    }
    __syncthreads();

    // ---- layer 4 + loss: 4 threads per point, 32 terms each ----
    {
        const int pl = tid >> 2;                              // logical point
        const int prow = (pl & ~15) | phi16(pl & 15);         // physical A row
        const int jb = (tid & 3) * 32;
        float s = 0.f;
        #pragma unroll
        for (int g = 0; g < 4; ++g) {
            uint4 u = *(const uint4*)&A[prow * LDA + jb + g * 8];
            float4 wa = *(const float4*)(W4 + jb + g * 8);
            float4 wb = *(const float4*)(W4 + jb + g * 8 + 4);
            s += __uint_as_float(u.x << 16)          * wa.x;
            s += __uint_as_float(u.x & 0xffff0000u)  * wa.y;
            s += __uint_as_float(u.y << 16)          * wa.z;
            s += __uint_as_float(u.y & 0xffff0000u)  * wa.w;
            s += __uint_as_float(u.z << 16)          * wb.x;
            s += __uint_as_float(u.z & 0xffff0000u)  * wb.y;
            s += __uint_as_float(u.w << 16)          * wb.z;
            s += __uint_as_float(u.w & 0xffff0000u)  * wb.w;
        }
        s += __shfl_xor(s, 1, 64);
        s += __shfl_xor(s, 2, 64);
        float e2 = 0.f;
        if ((tid & 3) == 0) {
            float recon = s + b4[0];
            float img = images[(b << 16) + (r << 8) + c0 + pl];
            float err = img - recon;
            e2 = err * err;
        }
        #pragma unroll
        for (int off = 4; off < 64; off <<= 1)
            e2 += __shfl_xor(e2, off, 64);
        if (lane == 0)
            atomicAdd(&partials[bid & 1023], e2);
    }

    // ---- last block finishes the reduction (saves a kernel launch) ----
    __threadfence();
    if (tid == 0)
        isLast = (atomicAdd(counter, 1u) == (unsigned)(gridDim.x - 1)) ? 1u : 0u;
    __syncthreads();
    if (isLast) {
        float s = __hip_atomic_load(&partials[tid],       __ATOMIC_RELAXED, __HIP_MEMORY_SCOPE_AGENT)
                + __hip_atomic_load(&partials[tid + 512], __ATOMIC_RELAXED, __HIP_MEMORY_SCOPE_AGENT);
        #pragma unroll
        for (int off = 1; off < 64; off <<= 1)
            s += __shfl_xor(s, off, 64);
        if (lane == 0) red[w] = s;
        __syncthreads();
        if (tid == 0) {
            float tot = 0.f;
            #pragma unroll
            for (int i = 0; i < 8; ++i) tot += red[i];
            out[0] = tot * (1.f / 1048576.f);
        }
    }
}

extern "C" void kernel_launch(void* const* d_in, const int* in_sizes, int n_in,
                              void* d_out, int out_size, void* d_ws, size_t ws_size,
                              hipStream_t stream)
{
    const float* images = (const float*)d_in[0];
    const float* W1 = (const float*)d_in[1];
    const float* b1 = (const float*)d_in[2];
    const float* W2 = (const float*)d_in[3];
    const float* b2 = (const float*)d_in[4];
    const float* W3 = (const float*)d_in[5];
    const float* b3 = (const float*)d_in[6];
    const float* W4 = (const float*)d_in[7];
    const float* b4 = (const float*)d_in[8];
    const int*   np = (const int*)d_in[10];

    unsigned short* w2t = (unsigned short*)d_ws;                     // 32 KB
    unsigned short* w3t = w2t + 128 * 128;                           // 32 KB
    float* partials = (float*)((char*)d_ws + 65536);                 // 4 KB
    unsigned int* counter = (unsigned int*)((char*)d_ws + 65536 + 4096);

    prep_kernel<<<128, 256, 0, stream>>>(W2, W3, w2t, w3t, partials, counter);
    main_kernel<<<BATCH * 256 * 2, 512, 0, stream>>>(
        images, W1, b1, b2, b3, W4, b4, np, w2t, w3t, partials, counter, (float*)d_out);
}

// Round 4
// 1099.736 us; speedup vs baseline: 1.2650x; 1.2650x over previous
//
#include <hip/hip_runtime.h>
#include <hip/hip_bf16.h>

// SurfaceLoss: 16x256x256 grid through 3->128->128->128->1 tanh MLP, MSE vs images.
// R4: fix R3's register spill (WRITE_SIZE 84MB, SGPR 48 = scratch SRD):
//     launch_bounds(512,6) -> 85-VGPR cap (was 64, too tight for rational tanh),
//     and single wf[] live range (reload W3 frags into same regs, -16 peak regs).
//     Keeps: rational transcendental-free tanh, phi swizzle, 2-launch structure.

#define BATCH 16
#define LDA 136                 // padded LDS row stride (bf16 elems); rows 16B-aligned for b128
#define STEP (256.0f / 255.0f)  // linspace(-128,128,256) step

typedef __bf16 v8bf __attribute__((ext_vector_type(8)));
typedef float  v4f  __attribute__((ext_vector_type(4)));
typedef float  v2f  __attribute__((ext_vector_type(2)));

__device__ __forceinline__ unsigned short f2bf(float f) {
    unsigned int u = __float_as_uint(f);
    unsigned int r = (u + 0x7fffu + ((u >> 16) & 1u)) >> 16;
    return (unsigned short)r;
}

#if __has_builtin(__builtin_amdgcn_cvt_pk_bf16_f32)
__device__ __forceinline__ unsigned int pack2bf(float a, float b) {
    auto p = __builtin_amdgcn_cvt_pk_bf16_f32(a, b);   // lo=a, hi=b
    union { decltype(p) v; unsigned int u; } c; c.v = p;
    return c.u;
}
#else
__device__ __forceinline__ unsigned int pack2bf(float a, float b) {
    return (unsigned)f2bf(a) | ((unsigned)f2bf(b) << 16);
}
#endif

__device__ __forceinline__ v2f V2(float c) { return (v2f){c, c}; }

#if __has_builtin(__builtin_elementwise_fma)
#define FMA2(a, b, c) __builtin_elementwise_fma((a), (b), (c))
#else
__device__ __forceinline__ v2f FMA2(v2f a, v2f b, v2f c) {
    v2f r; r.x = __builtin_fmaf(a.x, b.x, c.x); r.y = __builtin_fmaf(a.y, b.y, c.y); return r;
}
#endif

// Two tanh at once: Eigen/XLA fast-tanh rational, all full-rate fp32.
// Division replaced by bit-trick reciprocal seed + 2 Newton steps (~7e-6 rel).
__device__ __forceinline__ v2f tanh2(v2f x) {
    x.x = __builtin_amdgcn_fmed3f(x.x, -7.90531111f, 7.90531111f);
    x.y = __builtin_amdgcn_fmed3f(x.y, -7.90531111f, 7.90531111f);
    v2f x2 = x * x;
    v2f p = FMA2(x2, V2(-2.76076847742355e-16f), V2(2.00018790482477e-13f));
    p = FMA2(x2, p, V2(-8.60467152213735e-11f));
    p = FMA2(x2, p, V2(5.12229709037114e-08f));
    p = FMA2(x2, p, V2(1.48572235717979e-05f));
    p = FMA2(x2, p, V2(6.37261928875436e-04f));
    p = FMA2(x2, p, V2(4.89352455891786e-03f));
    p = p * x;
    v2f q = FMA2(x2, V2(1.19825839466702e-06f), V2(1.18534705686654e-04f));
    q = FMA2(x2, q, V2(2.26843463243900e-03f));
    q = FMA2(x2, q, V2(4.89352518554385e-03f));
    union { v2f f; unsigned int u[2]; } cq, cr;
    cq.f = q;
    cr.u[0] = 0x7EF311C3u - cq.u[0];   // q > 0 always
    cr.u[1] = 0x7EF311C3u - cq.u[1];
    v2f r = cr.f;
    r = r * FMA2(-q, r, V2(2.0f));
    r = r * FMA2(-q, r, V2(2.0f));
    return p * r;
}

// phi: within-16 row permutation; epilogue's 4 quads land on 4 disjoint bank octets.
__device__ __forceinline__ int phi16(int m) {
    return ((m >> 2) << 1) | (m & 1) | ((m & 2) << 2);
}

// ---- prep: W2,W3 (128x128 fp32 [k][n]) -> bf16 [n][k]; zero partials+counter ----
__global__ __launch_bounds__(256) void prep_kernel(
    const float* __restrict__ W2, const float* __restrict__ W3,
    unsigned short* __restrict__ w2t, unsigned short* __restrict__ w3t,
    float* __restrict__ partials, unsigned int* __restrict__ counter)
{
    int o = blockIdx.x * 256 + threadIdx.x;
    if (o < 1024) partials[o] = 0.f;
    if (o == 0) *counter = 0u;
    const float* src = (o < 16384) ? W2 : W3;
    unsigned short* dst = (o < 16384) ? w2t : w3t;
    int e = o & 16383;
    int k = e >> 7, n = e & 127;
    dst[n * 128 + k] = f2bf(src[e]);
}

// ---- main: one block (512 thr, 8 waves) = 128 consecutive pixels of one image row ----
__global__ __launch_bounds__(512, 6) void main_kernel(
    const float* __restrict__ images,
    const float* __restrict__ W1, const float* __restrict__ b1,
    const float* __restrict__ b2, const float* __restrict__ b3,
    const float* __restrict__ W4, const float* __restrict__ b4,
    const int*   __restrict__ np,
    const unsigned short* __restrict__ w2t,
    const unsigned short* __restrict__ w3t,
    float* __restrict__ partials, unsigned int* __restrict__ counter,
    float* __restrict__ out)
{
    __shared__ unsigned short A[128 * LDA];
    __shared__ float red[8];
    __shared__ unsigned int isLast;

    const int tid  = threadIdx.x;
    const int lane = tid & 63;
    const int w    = tid >> 6;        // wave 0..7, owns 16 output cols
    const int l15  = lane & 15;
    const int quad = lane >> 4;
    const int l15p = phi16(l15);      // physical row-within-16 for fragment reads

    const int bid = blockIdx.x;
    const int b   = bid >> 9;          // 512 blocks per image
    const int rem = bid & 511;
    const int r   = rem >> 1;          // image row (x index)
    const int c0  = (rem & 1) << 7;    // y base

    const float tv = (float)(b + np[0] * BATCH);
    const float xv = -128.f + (float)r * STEP;

    // ---- layer 1 (fp32): each thread 2 cols x 16 points, pairwise ----
    {
        const int lo = tid & 63;       // col pair j0 = 2*lo
        const int j0 = lo * 2;
        const int w16 = w * 16;        // this wave's 16 point-rows
        unsigned int* A32 = (unsigned int*)A;
        v2f wx2 = *(const v2f*)(W1 + j0);
        v2f wy2 = *(const v2f*)(W1 + 128 + j0);
        v2f wt2 = *(const v2f*)(W1 + 256 + j0);
        v2f bb2 = *(const v2f*)(b1 + j0);
        v2f cj = FMA2(V2(xv), wx2, FMA2(V2(tv), wt2, bb2));
        #pragma unroll
        for (int pi = 0; pi < 16; ++pi) {
            const int pl = w16 + pi;                         // logical point row
            const float yv = fmaf((float)(c0 + pl), STEP, -128.f);
            v2f t = tanh2(FMA2(V2(yv), wy2, cj));
            A32[(w16 + phi16(pi)) * (LDA / 2) + lo] = pack2bf(t.x, t.y);  // conflict-free b32
        }
    }
    __syncthreads();

    const int colw = w * 16 + l15;     // this lane's output column

    // ---- W2 B-fragments from L2 ([n][k] layout) ----
    v8bf wf[4];
    #pragma unroll
    for (int ks = 0; ks < 4; ++ks)
        wf[ks] = *(const v8bf*)(w2t + colw * 128 + ks * 32 + quad * 8);

    // ---- layer 2 MFMA ----
    v4f acc[8];
    #pragma unroll
    for (int mt = 0; mt < 8; ++mt) acc[mt] = (v4f){0.f, 0.f, 0.f, 0.f};
    #pragma unroll
    for (int ks = 0; ks < 4; ++ks) {
        #pragma unroll
        for (int mt = 0; mt < 8; ++mt) {
            v8bf af = *(const v8bf*)&A[(mt * 16 + l15p) * LDA + ks * 32 + quad * 8];
            acc[mt] = __builtin_amdgcn_mfma_f32_16x16x32_bf16(af, wf[ks], acc[mt], 0, 0, 0);
        }
    }

    // reload W3 fragments into the SAME registers (no overlapping live ranges)
    #pragma unroll
    for (int ks = 0; ks < 4; ++ks)
        wf[ks] = *(const v8bf*)(w3t + colw * 128 + ks * 32 + quad * 8);
    __syncthreads();   // all waves done reading A

    // ---- epilogue 2: tanh(acc + b2) -> A, phi rows ----
    {
        float bi = b2[colw];
        #pragma unroll
        for (int mt = 0; mt < 8; ++mt) {
            v2f zlo; zlo.x = acc[mt][0]; zlo.y = acc[mt][1];
            v2f zhi; zhi.x = acc[mt][2]; zhi.y = acc[mt][3];
            v2f t01 = tanh2(zlo + V2(bi));
            v2f t23 = tanh2(zhi + V2(bi));
            unsigned u01 = pack2bf(t01.x, t01.y);
            unsigned u23 = pack2bf(t23.x, t23.y);
            int rowb = (mt * 16 + quad * 2) * LDA + colw;   // phi: rg{0,1,2,3}->{0,1,8,9}
            A[rowb]           = (unsigned short)u01;
            A[rowb + LDA]     = (unsigned short)(u01 >> 16);
            A[rowb + 8 * LDA] = (unsigned short)u23;
            A[rowb + 9 * LDA] = (unsigned short)(u23 >> 16);
        }
    }
    __syncthreads();

    // ---- layer 3 MFMA ----
    #pragma unroll
    for (int mt = 0; mt < 8; ++mt) acc[mt] = (v4f){0.f, 0.f, 0.f, 0.f};
    #pragma unroll
    for (int ks = 0; ks < 4; ++ks) {
        #pragma unroll
        for (int mt = 0; mt < 8; ++mt) {
            v8bf af = *(const v8bf*)&A[(mt * 16 + l15p) * LDA + ks * 32 + quad * 8];
            acc[mt] = __builtin_amdgcn_mfma_f32_16x16x32_bf16(af, wf[ks], acc[mt], 0, 0, 0);
        }
    }
    __syncthreads();

    // ---- epilogue 3 ----
    {
        float bi = b3[colw];
        #pragma unroll
        for (int mt = 0; mt < 8; ++mt) {
            v2f zlo; zlo.x = acc[mt][0]; zlo.y = acc[mt][1];
            v2f zhi; zhi.x = acc[mt][2]; zhi.y = acc[mt][3];
            v2f t01 = tanh2(zlo + V2(bi));
            v2f t23 = tanh2(zhi + V2(bi));
            unsigned u01 = pack2bf(t01.x, t01.y);
            unsigned u23 = pack2bf(t23.x, t23.y);
            int rowb = (mt * 16 + quad * 2) * LDA + colw;
            A[rowb]           = (unsigned short)u01;
            A[rowb + LDA]     = (unsigned short)(u01 >> 16);
            A[rowb + 8 * LDA] = (unsigned short)u23;
            A[rowb + 9 * LDA] = (unsigned short)(u23 >> 16);
        }
    }
    __syncthreads();

    // ---- layer 4 + loss: 4 threads per point, 32 terms each ----
    {
        const int pl = tid >> 2;                              // logical point
        const int prow = (pl & ~15) | phi16(pl & 15);         // physical A row
        const int jb = (tid & 3) * 32;
        float s = 0.f;
        #pragma unroll
        for (int g = 0; g < 4; ++g) {
            uint4 u = *(const uint4*)&A[prow * LDA + jb + g * 8];
            float4 wa = *(const float4*)(W4 + jb + g * 8);
            float4 wb = *(const float4*)(W4 + jb + g * 8 + 4);
            s += __uint_as_float(u.x << 16)          * wa.x;
            s += __uint_as_float(u.x & 0xffff0000u)  * wa.y;
            s += __uint_as_float(u.y << 16)          * wa.z;
            s += __uint_as_float(u.y & 0xffff0000u)  * wa.w;
            s += __uint_as_float(u.z << 16)          * wb.x;
            s += __uint_as_float(u.z & 0xffff0000u)  * wb.y;
            s += __uint_as_float(u.w << 16)          * wb.z;
            s += __uint_as_float(u.w & 0xffff0000u)  * wb.w;
        }
        s += __shfl_xor(s, 1, 64);
        s += __shfl_xor(s, 2, 64);
        float e2 = 0.f;
        if ((tid & 3) == 0) {
            float recon = s + b4[0];
            float img = images[(b << 16) + (r << 8) + c0 + pl];
            float err = img - recon;
            e2 = err * err;
        }
        #pragma unroll
        for (int off = 4; off < 64; off <<= 1)
            e2 += __shfl_xor(e2, off, 64);
        if (lane == 0)
            atomicAdd(&partials[bid & 1023], e2);
    }

    // ---- last block finishes the reduction ----
    __threadfence();
    if (tid == 0)
        isLast = (atomicAdd(counter, 1u) == (unsigned)(gridDim.x - 1)) ? 1u : 0u;
    __syncthreads();
    if (isLast) {
        __threadfence();   // acquire: make all blocks' partials visible
        float s = __hip_atomic_load(&partials[tid],       __ATOMIC_RELAXED, __HIP_MEMORY_SCOPE_AGENT)
                + __hip_atomic_load(&partials[tid + 512], __ATOMIC_RELAXED, __HIP_MEMORY_SCOPE_AGENT);
        #pragma unroll
        for (int off = 1; off < 64; off <<= 1)
            s += __shfl_xor(s, off, 64);
        if (lane == 0) red[w] = s;
        __syncthreads();
        if (tid == 0) {
            float tot = 0.f;
            #pragma unroll
            for (int i = 0; i < 8; ++i) tot += red[i];
            out[0] = tot * (1.f / 1048576.f);
        }
    }
}

extern "C" void kernel_launch(void* const* d_in, const int* in_sizes, int n_in,
                              void* d_out, int out_size, void* d_ws, size_t ws_size,
                              hipStream_t stream)
{
    const float* images = (const float*)d_in[0];
    const float* W1 = (const float*)d_in[1];
    const float* b1 = (const float*)d_in[2];
    const float* W2 = (const float*)d_in[3];
    const float* b2 = (const float*)d_in[4];
    const float* W3 = (const float*)d_in[5];
    const float* b3 = (const float*)d_in[6];
    const float* W4 = (const float*)d_in[7];
    const float* b4 = (const float*)d_in[8];
    const int*   np = (const int*)d_in[10];

    unsigned short* w2t = (unsigned short*)d_ws;                     // 32 KB
    unsigned short* w3t = w2t + 128 * 128;                           // 32 KB
    float* partials = (float*)((char*)d_ws + 65536);                 // 4 KB
    unsigned int* counter = (unsigned int*)((char*)d_ws + 65536 + 4096);

    prep_kernel<<<128, 256, 0, stream>>>(W2, W3, w2t, w3t, partials, counter);
    main_kernel<<<BATCH * 256 * 2, 512, 0, stream>>>(
        images, W1, b1, b2, b3, W4, b4, np, w2t, w3t, partials, counter, (float*)d_out);
}

// Round 5
// 1081.193 us; speedup vs baseline: 1.2867x; 1.0172x over previous
//
#include <hip/hip_runtime.h>
#include <hip/hip_bf16.h>

// SurfaceLoss: 16x256x256 grid through 3->128->128->128->1 tanh MLP, MSE vs images.
// R5: revert main to R2's proven structure (exp2-tanh + KS-folding, (512,8), LDA 136)
//     after R3/R4 post-mortem showed the rational-tanh unroll bloated code to ~25KB
//     and thrashed L1I (VALUBusy 71%->15% with all pipes idle). Keep R4's 2-launch
//     structure (prep zeroes, main's last block reduces) which cut overhead 52->10us.

#define BATCH 16
#define LDA 136                 // padded LDS row stride (bf16 elems)
#define STEP (256.0f / 255.0f)  // linspace(-128,128,256) step
#define KS 2.8853900817779268f  // 2*log2(e): tanh(z) = 1 - 2/(exp2(KS*z)+1)

typedef __bf16 v8bf __attribute__((ext_vector_type(8)));
typedef float  v4f  __attribute__((ext_vector_type(4)));

__device__ __forceinline__ unsigned short f2bf(float f) {
    unsigned int u = __float_as_uint(f);
    unsigned int r = (u + 0x7fffu + ((u >> 16) & 1u)) >> 16;
    return (unsigned short)r;
}

#if __has_builtin(__builtin_amdgcn_cvt_pk_bf16_f32)
__device__ __forceinline__ unsigned int pack2bf(float a, float b) {
    auto p = __builtin_amdgcn_cvt_pk_bf16_f32(a, b);   // lo=a, hi=b
    union { decltype(p) v; unsigned int u; } c; c.v = p;
    return c.u;
}
#else
__device__ __forceinline__ unsigned int pack2bf(float a, float b) {
    return (unsigned)f2bf(a) | ((unsigned)f2bf(b) << 16);
}
#endif

// input already scaled by KS; exact at +/-inf ends, no NaN possible for finite z
__device__ __forceinline__ float tanh_pre(float zk) {
    float e = __builtin_amdgcn_exp2f(zk);
    float r = __builtin_amdgcn_rcpf(e + 1.f);
    return fmaf(-2.f, r, 1.f);
}

// ---- prep: W2,W3 (128x128 fp32 [k][n]) -> bf16 [n][k] pre-scaled by KS;
//      zero partials + counter ----
__global__ __launch_bounds__(256) void prep_kernel(
    const float* __restrict__ W2, const float* __restrict__ W3,
    unsigned short* __restrict__ w2t, unsigned short* __restrict__ w3t,
    float* __restrict__ partials, unsigned int* __restrict__ counter)
{
    int o = blockIdx.x * 256 + threadIdx.x;
    if (o < 1024) partials[o] = 0.f;
    if (o == 0) *counter = 0u;
    const float* src = (o < 16384) ? W2 : W3;
    unsigned short* dst = (o < 16384) ? w2t : w3t;
    int e = o & 16383;
    int k = e >> 7, n = e & 127;
    dst[n * 128 + k] = f2bf(src[e] * KS);
}

// ---- main: one block (512 thr, 8 waves) = 128 consecutive pixels of one image row ----
__global__ __launch_bounds__(512, 8) void main_kernel(
    const float* __restrict__ images,
    const float* __restrict__ W1, const float* __restrict__ b1,
    const float* __restrict__ b2, const float* __restrict__ b3,
    const float* __restrict__ W4, const float* __restrict__ b4,
    const int*   __restrict__ np,
    const unsigned short* __restrict__ w2t,
    const unsigned short* __restrict__ w3t,
    float* __restrict__ partials, unsigned int* __restrict__ counter,
    float* __restrict__ out)
{
    __shared__ unsigned short A[128 * LDA];
    __shared__ float red[8];
    __shared__ unsigned int isLast;

    const int tid  = threadIdx.x;
    const int lane = tid & 63;
    const int w    = tid >> 6;        // wave 0..7, owns 16 output cols
    const int l15  = lane & 15;
    const int quad = lane >> 4;

    const int bid = blockIdx.x;
    const int b   = bid >> 9;          // 512 blocks per image
    const int rem = bid & 511;
    const int r   = rem >> 1;          // image row (x index)
    const int c0  = (rem & 1) << 7;    // y base

    const float tv = (float)(b + np[0] * BATCH);
    const float xv = -128.f + (float)r * STEP;

    // ---- layer 1 (fp32, pre-scaled by KS): each thread 4 cols x 8 points ----
    {
        const int lo = tid & 31, hi = tid >> 5;
        const int j0 = lo * 4, p0 = hi * 8;
        float4 wx = *(const float4*)(W1 + j0);
        float4 wy = *(const float4*)(W1 + 128 + j0);
        float4 wt = *(const float4*)(W1 + 256 + j0);
        float4 bb = *(const float4*)(b1 + j0);
        float cj0 = KS * fmaf(xv, wx.x, fmaf(tv, wt.x, bb.x));
        float cj1 = KS * fmaf(xv, wx.y, fmaf(tv, wt.y, bb.y));
        float cj2 = KS * fmaf(xv, wx.z, fmaf(tv, wt.z, bb.z));
        float cj3 = KS * fmaf(xv, wx.w, fmaf(tv, wt.w, bb.w));
        float wy0 = KS * wy.x, wy1 = KS * wy.y, wy2 = KS * wy.z, wy3 = KS * wy.w;
        #pragma unroll
        for (int pi = 0; pi < 8; ++pi) {
            const int p = p0 + pi;
            const float yv = fmaf((float)(c0 + p), STEP, -128.f);
            float t0 = tanh_pre(fmaf(yv, wy0, cj0));
            float t1 = tanh_pre(fmaf(yv, wy1, cj1));
            float t2 = tanh_pre(fmaf(yv, wy2, cj2));
            float t3 = tanh_pre(fmaf(yv, wy3, cj3));
            uint2 u = make_uint2(pack2bf(t0, t1), pack2bf(t2, t3));
            *(uint2*)&A[p * LDA + j0] = u;   // 8B store, conflict-free
        }
    }
    __syncthreads();

    const int colw = w * 16 + l15;     // this lane's output column

    // ---- W2 B-fragments from L2 ([n][k] layout, pre-scaled) ----
    v8bf wf[4];
    #pragma unroll
    for (int ks = 0; ks < 4; ++ks)
        wf[ks] = *(const v8bf*)(w2t + colw * 128 + ks * 32 + quad * 8);

    // ---- layer 2 MFMA ----
    v4f acc[8];
    #pragma unroll
    for (int mt = 0; mt < 8; ++mt) acc[mt] = (v4f){0.f, 0.f, 0.f, 0.f};
    #pragma unroll
    for (int ks = 0; ks < 4; ++ks) {
        #pragma unroll
        for (int mt = 0; mt < 8; ++mt) {
            v8bf af = *(const v8bf*)&A[(mt * 16 + l15) * LDA + ks * 32 + quad * 8];
            acc[mt] = __builtin_amdgcn_mfma_f32_16x16x32_bf16(af, wf[ks], acc[mt], 0, 0, 0);
        }
    }

    // prefetch W3 fragments
    v8bf w3f[4];
    #pragma unroll
    for (int ks = 0; ks < 4; ++ks)
        w3f[ks] = *(const v8bf*)(w3t + colw * 128 + ks * 32 + quad * 8);
    __syncthreads();   // all waves done reading A

    // ---- epilogue 2: tanh(acc + KS*b2) -> A (acc already KS-scaled) ----
    {
        float biK = b2[colw] * KS;
        #pragma unroll
        for (int mt = 0; mt < 8; ++mt) {
            float t0 = tanh_pre(acc[mt][0] + biK);
            float t1 = tanh_pre(acc[mt][1] + biK);
            float t2 = tanh_pre(acc[mt][2] + biK);
            float t3 = tanh_pre(acc[mt][3] + biK);
            unsigned u01 = pack2bf(t0, t1);
            unsigned u23 = pack2bf(t2, t3);
            int rowb = (mt * 16 + quad * 4) * LDA + colw;
            A[rowb]           = (unsigned short)u01;
            A[rowb + LDA]     = (unsigned short)(u01 >> 16);
            A[rowb + 2 * LDA] = (unsigned short)u23;
            A[rowb + 3 * LDA] = (unsigned short)(u23 >> 16);
        }
    }
    __syncthreads();

    // ---- layer 3 MFMA ----
    #pragma unroll
    for (int mt = 0; mt < 8; ++mt) acc[mt] = (v4f){0.f, 0.f, 0.f, 0.f};
    #pragma unroll
    for (int ks = 0; ks < 4; ++ks) {
        #pragma unroll
        for (int mt = 0; mt < 8; ++mt) {
            v8bf af = *(const v8bf*)&A[(mt * 16 + l15) * LDA + ks * 32 + quad * 8];
            acc[mt] = __builtin_amdgcn_mfma_f32_16x16x32_bf16(af, w3f[ks], acc[mt], 0, 0, 0);
        }
    }
    __syncthreads();

    // ---- epilogue 3 ----
    {
        float biK = b3[colw] * KS;
        #pragma unroll
        for (int mt = 0; mt < 8; ++mt) {
            float t0 = tanh_pre(acc[mt][0] + biK);
            float t1 = tanh_pre(acc[mt][1] + biK);
            float t2 = tanh_pre(acc[mt][2] + biK);
            float t3 = tanh_pre(acc[mt][3] + biK);
            unsigned u01 = pack2bf(t0, t1);
            unsigned u23 = pack2bf(t2, t3);
            int rowb = (mt * 16 + quad * 4) * LDA + colw;
            A[rowb]           = (unsigned short)u01;
            A[rowb + LDA]     = (unsigned short)(u01 >> 16);
            A[rowb + 2 * LDA] = (unsigned short)u23;
            A[rowb + 3 * LDA] = (unsigned short)(u23 >> 16);
        }
    }
    __syncthreads();

    // ---- layer 4 + loss: 4 threads per point, 32 terms each ----
    {
        const int p  = tid >> 2;
        const int jb = (tid & 3) * 32;
        float s = 0.f;
        #pragma unroll
        for (int g = 0; g < 4; ++g) {
            uint4 u = *(const uint4*)&A[p * LDA + jb + g * 8];
            float4 wa = *(const float4*)(W4 + jb + g * 8);
            float4 wb = *(const float4*)(W4 + jb + g * 8 + 4);
            s += __uint_as_float(u.x << 16)          * wa.x;
            s += __uint_as_float(u.x & 0xffff0000u)  * wa.y;
            s += __uint_as_float(u.y << 16)          * wa.z;
            s += __uint_as_float(u.y & 0xffff0000u)  * wa.w;
            s += __uint_as_float(u.z << 16)          * wb.x;
            s += __uint_as_float(u.z & 0xffff0000u)  * wb.y;
            s += __uint_as_float(u.w << 16)          * wb.z;
            s += __uint_as_float(u.w & 0xffff0000u)  * wb.w;
        }
        s += __shfl_xor(s, 1, 64);
        s += __shfl_xor(s, 2, 64);
        float e2 = 0.f;
        if ((tid & 3) == 0) {
            float recon = s + b4[0];
            float img = images[(b << 16) + (r << 8) + c0 + p];
            float err = img - recon;
            e2 = err * err;
        }
        #pragma unroll
        for (int off = 4; off < 64; off <<= 1)
            e2 += __shfl_xor(e2, off, 64);
        if (lane == 0)
            atomicAdd(&partials[bid & 1023], e2);
    }

    // ---- last block finishes the reduction (saves launch overhead) ----
    __threadfence();
    if (tid == 0)
        isLast = (atomicAdd(counter, 1u) == (unsigned)(gridDim.x - 1)) ? 1u : 0u;
    __syncthreads();
    if (isLast) {
        __threadfence();
        float s = __hip_atomic_load(&partials[tid],       __ATOMIC_RELAXED, __HIP_MEMORY_SCOPE_AGENT)
                + __hip_atomic_load(&partials[tid + 512], __ATOMIC_RELAXED, __HIP_MEMORY_SCOPE_AGENT);
        #pragma unroll
        for (int off = 1; off < 64; off <<= 1)
            s += __shfl_xor(s, off, 64);
        if (lane == 0) red[w] = s;
        __syncthreads();
        if (tid == 0) {
            float tot = 0.f;
            #pragma unroll
            for (int i = 0; i < 8; ++i) tot += red[i];
            out[0] = tot * (1.f / 1048576.f);
        }
    }
}

extern "C" void kernel_launch(void* const* d_in, const int* in_sizes, int n_in,
                              void* d_out, int out_size, void* d_ws, size_t ws_size,
                              hipStream_t stream)
{
    const float* images = (const float*)d_in[0];
    const float* W1 = (const float*)d_in[1];
    const float* b1 = (const float*)d_in[2];
    const float* W2 = (const float*)d_in[3];
    const float* b2 = (const float*)d_in[4];
    const float* W3 = (const float*)d_in[5];
    const float* b3 = (const float*)d_in[6];
    const float* W4 = (const float*)d_in[7];
    const float* b4 = (const float*)d_in[8];
    const int*   np = (const int*)d_in[10];

    unsigned short* w2t = (unsigned short*)d_ws;                     // 32 KB
    unsigned short* w3t = w2t + 128 * 128;                           // 32 KB
    float* partials = (float*)((char*)d_ws + 65536);                 // 4 KB
    unsigned int* counter = (unsigned int*)((char*)d_ws + 65536 + 4096);

    prep_kernel<<<128, 256, 0, stream>>>(W2, W3, w2t, w3t, partials, counter);
    main_kernel<<<BATCH * 256 * 2, 512, 0, stream>>>(
        images, W1, b1, b2, b3, W4, b4, np, w2t, w3t, partials, counter, (float*)d_out);
}

// Round 6
// 235.745 us; speedup vs baseline: 5.9013x; 4.5863x over previous
//
#include <hip/hip_runtime.h>
#include <hip/hip_bf16.h>

// SurfaceLoss: 16x256x256 grid through 3->128->128->128->1 tanh MLP, MSE vs images.
// R6: revert to R2's proven 3-dispatch structure. R3/R4/R5 post-mortem isolated the
//     ~880us regression to the per-block __threadfence() tail (agent-scope fence =
//     buffer_wbl2+inv L2 flush on gfx950, executed by every wave of every block).
//     NO in-kernel device fences; ordering via kernel boundaries. Prep zeroes
//     partials (saves the memset dispatch vs R2).

#define BATCH 16
#define LDA 136                 // padded LDS row stride (bf16 elems)
#define STEP (256.0f / 255.0f)  // linspace(-128,128,256) step
#define KS 2.8853900817779268f  // 2*log2(e): tanh(z) = 1 - 2/(exp2(KS*z)+1)

typedef __bf16 v8bf __attribute__((ext_vector_type(8)));
typedef float  v4f  __attribute__((ext_vector_type(4)));

__device__ __forceinline__ unsigned short f2bf(float f) {
    unsigned int u = __float_as_uint(f);
    unsigned int r = (u + 0x7fffu + ((u >> 16) & 1u)) >> 16;
    return (unsigned short)r;
}

#if __has_builtin(__builtin_amdgcn_cvt_pk_bf16_f32)
__device__ __forceinline__ unsigned int pack2bf(float a, float b) {
    auto p = __builtin_amdgcn_cvt_pk_bf16_f32(a, b);   // lo=a, hi=b
    union { decltype(p) v; unsigned int u; } c; c.v = p;
    return c.u;
}
#else
__device__ __forceinline__ unsigned int pack2bf(float a, float b) {
    return (unsigned)f2bf(a) | ((unsigned)f2bf(b) << 16);
}
#endif

// input already scaled by KS; exact at +/-inf ends, no NaN possible for finite z
__device__ __forceinline__ float tanh_pre(float zk) {
    float e = __builtin_amdgcn_exp2f(zk);
    float r = __builtin_amdgcn_rcpf(e + 1.f);
    return fmaf(-2.f, r, 1.f);
}

// ---- prep: W2,W3 (128x128 fp32 [k][n]) -> bf16 [n][k] pre-scaled by KS; zero partials ----
__global__ __launch_bounds__(256) void prep_kernel(
    const float* __restrict__ W2, const float* __restrict__ W3,
    unsigned short* __restrict__ w2t, unsigned short* __restrict__ w3t,
    float* __restrict__ partials)
{
    int o = blockIdx.x * 256 + threadIdx.x;
    if (o < 1024) partials[o] = 0.f;
    const float* src = (o < 16384) ? W2 : W3;
    unsigned short* dst = (o < 16384) ? w2t : w3t;
    int e = o & 16383;
    int k = e >> 7, n = e & 127;
    dst[n * 128 + k] = f2bf(src[e] * KS);
}

// ---- main: one block (512 thr, 8 waves) = 128 consecutive pixels of one image row ----
__global__ __launch_bounds__(512, 8) void main_kernel(
    const float* __restrict__ images,
    const float* __restrict__ W1, const float* __restrict__ b1,
    const float* __restrict__ b2, const float* __restrict__ b3,
    const float* __restrict__ W4, const float* __restrict__ b4,
    const int*   __restrict__ np,
    const unsigned short* __restrict__ w2t,
    const unsigned short* __restrict__ w3t,
    float* __restrict__ partials)
{
    __shared__ unsigned short A[128 * LDA];

    const int tid  = threadIdx.x;
    const int lane = tid & 63;
    const int w    = tid >> 6;        // wave 0..7, owns 16 output cols
    const int l15  = lane & 15;
    const int quad = lane >> 4;

    const int bid = blockIdx.x;
    const int b   = bid >> 9;          // 512 blocks per image
    const int rem = bid & 511;
    const int r   = rem >> 1;          // image row (x index)
    const int c0  = (rem & 1) << 7;    // y base

    const float tv = (float)(b + np[0] * BATCH);
    const float xv = -128.f + (float)r * STEP;

    // ---- layer 1 (fp32, pre-scaled by KS): each thread 4 cols x 8 points ----
    {
        const int lo = tid & 31, hi = tid >> 5;
        const int j0 = lo * 4, p0 = hi * 8;
        float4 wx = *(const float4*)(W1 + j0);
        float4 wy = *(const float4*)(W1 + 128 + j0);
        float4 wt = *(const float4*)(W1 + 256 + j0);
        float4 bb = *(const float4*)(b1 + j0);
        float cj0 = KS * fmaf(xv, wx.x, fmaf(tv, wt.x, bb.x));
        float cj1 = KS * fmaf(xv, wx.y, fmaf(tv, wt.y, bb.y));
        float cj2 = KS * fmaf(xv, wx.z, fmaf(tv, wt.z, bb.z));
        float cj3 = KS * fmaf(xv, wx.w, fmaf(tv, wt.w, bb.w));
        float wy0 = KS * wy.x, wy1 = KS * wy.y, wy2 = KS * wy.z, wy3 = KS * wy.w;
        #pragma unroll
        for (int pi = 0; pi < 8; ++pi) {
            const int p = p0 + pi;
            const float yv = fmaf((float)(c0 + p), STEP, -128.f);
            float t0 = tanh_pre(fmaf(yv, wy0, cj0));
            float t1 = tanh_pre(fmaf(yv, wy1, cj1));
            float t2 = tanh_pre(fmaf(yv, wy2, cj2));
            float t3 = tanh_pre(fmaf(yv, wy3, cj3));
            uint2 u = make_uint2(pack2bf(t0, t1), pack2bf(t2, t3));
            *(uint2*)&A[p * LDA + j0] = u;   // 8B store, conflict-free
        }
    }
    __syncthreads();

    const int colw = w * 16 + l15;     // this lane's output column

    // ---- W2 B-fragments from L2 ([n][k] layout, pre-scaled) ----
    v8bf wf[4];
    #pragma unroll
    for (int ks = 0; ks < 4; ++ks)
        wf[ks] = *(const v8bf*)(w2t + colw * 128 + ks * 32 + quad * 8);

    // ---- layer 2 MFMA ----
    v4f acc[8];
    #pragma unroll
    for (int mt = 0; mt < 8; ++mt) acc[mt] = (v4f){0.f, 0.f, 0.f, 0.f};
    #pragma unroll
    for (int ks = 0; ks < 4; ++ks) {
        #pragma unroll
        for (int mt = 0; mt < 8; ++mt) {
            v8bf af = *(const v8bf*)&A[(mt * 16 + l15) * LDA + ks * 32 + quad * 8];
            acc[mt] = __builtin_amdgcn_mfma_f32_16x16x32_bf16(af, wf[ks], acc[mt], 0, 0, 0);
        }
    }

    // prefetch W3 fragments
    v8bf w3f[4];
    #pragma unroll
    for (int ks = 0; ks < 4; ++ks)
        w3f[ks] = *(const v8bf*)(w3t + colw * 128 + ks * 32 + quad * 8);
    __syncthreads();   // all waves done reading A

    // ---- epilogue 2: tanh(acc + KS*b2) -> A (acc already KS-scaled) ----
    {
        float biK = b2[colw] * KS;
        #pragma unroll
        for (int mt = 0; mt < 8; ++mt) {
            float t0 = tanh_pre(acc[mt][0] + biK);
            float t1 = tanh_pre(acc[mt][1] + biK);
            float t2 = tanh_pre(acc[mt][2] + biK);
            float t3 = tanh_pre(acc[mt][3] + biK);
            unsigned u01 = pack2bf(t0, t1);
            unsigned u23 = pack2bf(t2, t3);
            int rowb = (mt * 16 + quad * 4) * LDA + colw;
            A[rowb]           = (unsigned short)u01;
            A[rowb + LDA]     = (unsigned short)(u01 >> 16);
            A[rowb + 2 * LDA] = (unsigned short)u23;
            A[rowb + 3 * LDA] = (unsigned short)(u23 >> 16);
        }
    }
    __syncthreads();

    // ---- layer 3 MFMA ----
    #pragma unroll
    for (int mt = 0; mt < 8; ++mt) acc[mt] = (v4f){0.f, 0.f, 0.f, 0.f};
    #pragma unroll
    for (int ks = 0; ks < 4; ++ks) {
        #pragma unroll
        for (int mt = 0; mt < 8; ++mt) {
            v8bf af = *(const v8bf*)&A[(mt * 16 + l15) * LDA + ks * 32 + quad * 8];
            acc[mt] = __builtin_amdgcn_mfma_f32_16x16x32_bf16(af, w3f[ks], acc[mt], 0, 0, 0);
        }
    }
    __syncthreads();

    // ---- epilogue 3 ----
    {
        float biK = b3[colw] * KS;
        #pragma unroll
        for (int mt = 0; mt < 8; ++mt) {
            float t0 = tanh_pre(acc[mt][0] + biK);
            float t1 = tanh_pre(acc[mt][1] + biK);
            float t2 = tanh_pre(acc[mt][2] + biK);
            float t3 = tanh_pre(acc[mt][3] + biK);
            unsigned u01 = pack2bf(t0, t1);
            unsigned u23 = pack2bf(t2, t3);
            int rowb = (mt * 16 + quad * 4) * LDA + colw;
            A[rowb]           = (unsigned short)u01;
            A[rowb + LDA]     = (unsigned short)(u01 >> 16);
            A[rowb + 2 * LDA] = (unsigned short)u23;
            A[rowb + 3 * LDA] = (unsigned short)(u23 >> 16);
        }
    }
    __syncthreads();

    // ---- layer 4 + loss: 4 threads per point, 32 terms each ----
    {
        const int p  = tid >> 2;
        const int jb = (tid & 3) * 32;
        float s = 0.f;
        #pragma unroll
        for (int g = 0; g < 4; ++g) {
            uint4 u = *(const uint4*)&A[p * LDA + jb + g * 8];
            float4 wa = *(const float4*)(W4 + jb + g * 8);
            float4 wb = *(const float4*)(W4 + jb + g * 8 + 4);
            s += __uint_as_float(u.x << 16)          * wa.x;
            s += __uint_as_float(u.x & 0xffff0000u)  * wa.y;
            s += __uint_as_float(u.y << 16)          * wa.z;
            s += __uint_as_float(u.y & 0xffff0000u)  * wa.w;
            s += __uint_as_float(u.z << 16)          * wb.x;
            s += __uint_as_float(u.z & 0xffff0000u)  * wb.y;
            s += __uint_as_float(u.w << 16)          * wb.z;
            s += __uint_as_float(u.w & 0xffff0000u)  * wb.w;
        }
        s += __shfl_xor(s, 1, 64);
        s += __shfl_xor(s, 2, 64);
        float e2 = 0.f;
        if ((tid & 3) == 0) {
            float recon = s + b4[0];
            float img = images[(b << 16) + (r << 8) + c0 + p];
            float err = img - recon;
            e2 = err * err;
        }
        #pragma unroll
        for (int off = 4; off < 64; off <<= 1)
            e2 += __shfl_xor(e2, off, 64);
        if (lane == 0)
            atomicAdd(&partials[bid & 1023], e2);
    }
}

// ---- finish: reduce 1024 partials, scale by 1/(B*YS*XS) ----
__global__ __launch_bounds__(256) void finish_kernel(
    const float* __restrict__ partials, float* __restrict__ out)
{
    const int tid = threadIdx.x;
    float s = partials[tid] + partials[tid + 256] + partials[tid + 512] + partials[tid + 768];
    #pragma unroll
    for (int off = 1; off < 64; off <<= 1)
        s += __shfl_xor(s, off, 64);
    __shared__ float red[4];
    if ((tid & 63) == 0) red[tid >> 6] = s;
    __syncthreads();
    if (tid == 0)
        out[0] = (red[0] + red[1] + red[2] + red[3]) * (1.f / 1048576.f);
}

extern "C" void kernel_launch(void* const* d_in, const int* in_sizes, int n_in,
                              void* d_out, int out_size, void* d_ws, size_t ws_size,
                              hipStream_t stream)
{
    const float* images = (const float*)d_in[0];
    const float* W1 = (const float*)d_in[1];
    const float* b1 = (const float*)d_in[2];
    const float* W2 = (const float*)d_in[3];
    const float* b2 = (const float*)d_in[4];
    const float* W3 = (const float*)d_in[5];
    const float* b3 = (const float*)d_in[6];
    const float* W4 = (const float*)d_in[7];
    const float* b4 = (const float*)d_in[8];
    const int*   np = (const int*)d_in[10];

    unsigned short* w2t = (unsigned short*)d_ws;                     // 32 KB
    unsigned short* w3t = w2t + 128 * 128;                           // 32 KB
    float* partials = (float*)((char*)d_ws + 65536);                 // 4 KB

    prep_kernel<<<128, 256, 0, stream>>>(W2, W3, w2t, w3t, partials);
    main_kernel<<<BATCH * 256 * 2, 512, 0, stream>>>(
        images, W1, b1, b2, b3, W4, b4, np, w2t, w3t, partials);
    finish_kernel<<<1, 256, 0, stream>>>(partials, (float*)d_out);
}